// Round 5
// baseline (62038.562 us; speedup 1.0000x reference)
//
#include <hip/hip_runtime.h>
#include <math.h>

// ---------------- problem constants ----------------
#define NZ 8
#define T_H 36
#define NVAR 502        // permuted variable count
#define MCON 769
#define NITERS 150
#define SIGMA 1e-6f
#define BIGINF 1e20f
#define ROWS 2          // batch rows per ADMM block

// constraint row offsets
#define R_XLB 9
#define R_XUB 81
#define R_UBOX 153
#define R_UEQ 223
#define R_DYN 275
#define R_SDYN 555
#define R_SLB 590
#define R_SUB 625
#define R_TGT 660
#define R_XSNN 661
#define R_SSNN 733

// global-var offsets (original ordering)
#define NUOFF 288
#define NSOFF 358
#define NXSOFF 394
#define NSSOFF 466

// ws layout (float offsets)
#define OFF_A      0          // A[769][512] permuted cols
#define OFF_CSRV   393728     // [769][12]
#define OFF_CSRC   402956     // [769][12] ints
#define OFF_CSCV   412184     // [502][16]
#define OFF_CSCR   420216     // [502][16] ints
#define OFF_M      428248     // M[502][512]
#define OFF_SINV   685272     // 36 * 14*14   Sinv_t (symmetric, zero-padded)
#define OFF_G      692328     // 36 * 14*14   G_t[i][j] (t>=1 used)
#define OFF_GT     699384     // 36 * 14*14   G_t[i][j] stored [t][j*14+i]
#define OFF_L0     956408     // [769]
#define OFF_U0     957177     // [769]

// permuted column: per-timestep blocks [z(8), u(2), s(1), xs(2), ss(1)], t=35 has no u
__device__ __forceinline__ int pcol(int v){
    if (v < 288){ int t = v >> 3, j = v & 7; return 14*t + j; }
    if (v < 358){ int q = v - 288; int t = q >> 1, k = q & 1; return 14*t + 8 + k; }
    if (v < 394){ int t = v - 358; return (t < 35) ? (14*t + 10) : 498; }
    if (v < 466){ int q = v - 394; int t = q >> 1, k = q & 1; return (t < 35) ? (14*t + 11 + k) : (499 + k); }
    int t = v - 466; return (t < 35) ? (14*t + 13) : 501;
}

__device__ __forceinline__ float rho_of(int r){
    if (r <= 8) return 1000.f;
    if (r >= R_UEQ && r < R_SLB) return 1000.f;   // ueq, dyn, sdyn
    return 1.f;
}

__device__ __forceinline__ float pdiag_p(int p){
    if (p < 490){ int s = p % 14; return (s >= 11) ? 20000.f : 0.f; }
    int s = p - 490; return (s >= 9) ? 20000.f : 0.f;
}

// ---------------- K1: build permuted dense A ----------------
__global__ __launch_bounds__(256) void k_build_A(const float* __restrict__ Az,
                                                 const float* __restrict__ Au,
                                                 const float* __restrict__ ZtoX,
                                                 float* __restrict__ ws){
    float* A = ws + OFF_A;
    int tid = threadIdx.x;
    for (int i = tid; i < 769*512; i += 256) A[i] = 0.f;
    __syncthreads();
    for (int i = tid; i < 8; i += 256) A[i*512 + pcol(i)] += 1.f;
    if (tid == 0) A[8*512 + pcol(NSOFF)] += 1.f;
    for (int idx = tid; idx < 576; idx += 256){
        int t = idx >> 4, k = (idx >> 3) & 1, j = idx & 7;
        float v = ZtoX[k*8 + j];
        int c = pcol(8*t + j);
        A[(R_XLB + 2*t + k)*512 + c] += v;
        A[(R_XUB + 2*t + k)*512 + c] += v;
    }
    for (int idx = tid; idx < 72; idx += 256){
        int c = pcol(NXSOFF + idx);
        A[(R_XLB + idx)*512 + c] += 1.f;
        A[(R_XUB + idx)*512 + c] -= 1.f;
    }
    for (int idx = tid; idx < 70; idx += 256) A[(R_UBOX + idx)*512 + pcol(NUOFF + idx)] += 1.f;
    for (int idx = tid; idx < 52; idx += 256){
        int i = idx >> 1, kk = idx & 1;
        int t = (i/3)*4 + (i%3) + 1;
        A[(R_UEQ + idx)*512 + pcol(NUOFF + 2*t + kk)]       += 1.f;
        A[(R_UEQ + idx)*512 + pcol(NUOFF + 2*(t-1) + kk)]   -= 1.f;
    }
    for (int idx = tid; idx < 2240; idx += 256){
        int t = idx/64 + 1, rem = idx % 64, j = rem >> 3, k = rem & 7;
        A[(R_DYN + 8*(t-1) + j)*512 + pcol(8*(t-1) + k)] += Az[j*8 + k];
    }
    for (int idx = tid; idx < 560; idx += 256){
        int t = idx/16 + 1, rem = idx % 16, j = rem >> 1, ju = rem & 1;
        A[(R_DYN + 8*(t-1) + j)*512 + pcol(NUOFF + 2*(t-1) + ju)] += Au[j*2 + ju];
    }
    for (int idx = tid; idx < 280; idx += 256){
        int t = (idx >> 3) + 1, j = idx & 7;
        A[(R_DYN + 8*(t-1) + j)*512 + pcol(8*t + j)] -= 1.f;
    }
    for (int idx = tid; idx < 35; idx += 256){
        int t = idx + 1; int rb = (R_SDYN + idx)*512;
        A[rb + pcol(NSOFF + t)]     += 1.f;
        A[rb + pcol(NSOFF + t - 1)] -= 1.f;
        A[rb + pcol(NUOFF + 2*(t-1))] += -0.05f;   // -0.2/NCC
    }
    for (int idx = tid; idx < 35; idx += 256){
        int t = idx + 1;
        A[(R_SLB + idx)*512 + pcol(NSOFF + t)]  += 1.f;
        A[(R_SLB + idx)*512 + pcol(NSSOFF + t)] += 1.f;
        A[(R_SUB + idx)*512 + pcol(NSOFF + t)]  += 1.f;
        A[(R_SUB + idx)*512 + pcol(NSSOFF + t)] -= 1.f;
    }
    if (tid == 0){
        A[R_TGT*512 + pcol(NSOFF + 35)]  += 1.f;
        A[R_TGT*512 + pcol(NSSOFF + 35)] += 1.f;
    }
    for (int idx = tid; idx < 72; idx += 256) A[(R_XSNN + idx)*512 + pcol(NXSOFF + idx)] += 1.f;
    for (int idx = tid; idx < 36; idx += 256) A[(R_SSNN + idx)*512 + pcol(NSSOFF + idx)] += 1.f;
}

// ---------------- K2: CSR(12) / CSC(16) from dense A ----------------
__global__ __launch_bounds__(256) void k_sparse(float* __restrict__ ws){
    const float* A = ws + OFF_A;
    float* crv = ws + OFF_CSRV; int* crc = (int*)(ws + OFF_CSRC);
    float* ccv = ws + OFF_CSCV; int* ccr = (int*)(ws + OFF_CSCR);
    int job = blockIdx.x*256 + threadIdx.x;
    if (job < 769){
        int r = job, n = 0;
        for (int c = 0; c < 502; ++c){
            float v = A[r*512 + c];
            if (v != 0.f && n < 12){ crv[r*12 + n] = v; crc[r*12 + n] = c; ++n; }
        }
        for (; n < 12; ++n){ crv[r*12 + n] = 0.f; crc[r*12 + n] = 0; }
    } else if (job < 1271){
        int c = job - 769, n = 0;
        for (int r = 0; r < 769; ++r){
            float v = A[r*512 + c];
            if (v != 0.f && n < 16){ ccv[c*16 + n] = v; ccr[c*16 + n] = r; ++n; }
        }
        for (; n < 16; ++n){ ccv[c*16 + n] = 0.f; ccr[c*16 + n] = 0; }
    }
}

// ---------------- K3: M = diag(P+sigma) + A^T rho A (permuted) ----------------
__global__ __launch_bounds__(256) void k_build_M(float* __restrict__ ws){
    const float* A = ws + OFF_A;
    const float* ccv = ws + OFF_CSCV; const int* ccr = (const int*)(ws + OFF_CSCR);
    float* M = ws + OFF_M;
    int gid = blockIdx.x*256 + threadIdx.x;
    int i = gid >> 9, j = gid & 511;
    if (j >= 502) return;
    float acc = 0.f;
    #pragma unroll
    for (int s = 0; s < 16; ++s){
        float v = ccv[i*16 + s]; int r = ccr[i*16 + s];
        acc += v * rho_of(r) * A[r*512 + j];
    }
    if (i == j) acc += pdiag_p(i) + SIGMA;
    M[i*512 + j] = acc;
}

// ---------------- K4: block-tridiagonal LDL factor (sequential over t) ----------------
__global__ __launch_bounds__(256) void k_factor(float* __restrict__ ws){
    const float* M = ws + OFF_M;
    float* Gout = ws + OFF_G;
    float* Sout = ws + OFF_SINV;
    __shared__ float Sp[196], Dl[196], Gl[196], fcol[14];
    __shared__ float aug[14*28];
    __shared__ float piv;
    int tid = threadIdx.x;
    for (int t = 0; t < 36; ++t){
        int bs = (t < 35) ? 14 : 12;
        int bo = 14*t;
        for (int idx = tid; idx < bs*bs; idx += 256){ int i = idx/bs, j = idx%bs; aug[i*28 + j] = M[(bo+i)*512 + bo + j]; }
        for (int idx = tid; idx < bs*bs; idx += 256){ int i = idx/bs, j = idx%bs; aug[i*28 + 14 + j] = (i==j) ? 1.f : 0.f; }
        if (t > 0){
            for (int idx = tid; idx < 196; idx += 256){ int i = idx/14, j = idx%14; Dl[idx] = (i < bs) ? M[(bo+i)*512 + (bo-14) + j] : 0.f; }
            __syncthreads();
            for (int idx = tid; idx < 196; idx += 256){
                int i = idx/14, j = idx%14; float a = 0.f;
                #pragma unroll
                for (int k = 0; k < 14; ++k) a += Dl[i*14 + k]*Sp[k*14 + j];
                Gl[idx] = a; Gout[t*196 + idx] = a;
            }
            __syncthreads();
            for (int idx = tid; idx < bs*bs; idx += 256){
                int i = idx/bs, j = idx%bs; float a = 0.f;
                #pragma unroll
                for (int k = 0; k < 14; ++k) a += Gl[i*14 + k]*Dl[j*14 + k];
                aug[i*28 + j] -= a;
            }
        }
        __syncthreads();
        for (int k = 0; k < bs; ++k){
            if (tid == 0) piv = 1.f/aug[k*28 + k];
            if (tid < bs) fcol[tid] = aug[tid*28 + k];
            __syncthreads();
            for (int j = tid; j < 2*bs; j += 256){ int col = (j < bs) ? j : (14 + j - bs); aug[k*28 + col] *= piv; }
            __syncthreads();
            for (int idx = tid; idx < bs*2*bs; idx += 256){
                int i = idx/(2*bs), jj = idx%(2*bs);
                int col = (jj < bs) ? jj : (14 + jj - bs);
                if (i != k) aug[i*28 + col] -= fcol[i]*aug[k*28 + col];
            }
            __syncthreads();
        }
        for (int idx = tid; idx < 196; idx += 256){
            int i = idx/14, j = idx%14;
            float v = (i < bs && j < bs) ? aug[i*28 + 14 + j] : 0.f;
            Sout[t*196 + idx] = v; Sp[idx] = v;
        }
        __syncthreads();
    }
}

// ---------------- K5: G^T layout for forward sweep ----------------
__global__ __launch_bounds__(256) void k_gt(float* __restrict__ ws){
    int idx = blockIdx.x*256 + threadIdx.x;
    if (idx >= 7056) return;
    int t = idx / 196, rem = idx % 196, i = rem / 14, j = rem % 14;
    ws[OFF_GT + t*196 + j*14 + i] = ws[OFF_G + t*196 + i*14 + j];
}

// ---------------- K6: batch-uniform bounds ----------------
__global__ __launch_bounds__(256) void k_bounds(const float* __restrict__ Xlb_p, const float* __restrict__ Xub_p,
                                                const float* __restrict__ slb_p, const float* __restrict__ sub_p,
                                                const float* __restrict__ tgt_p, float* __restrict__ ws){
    __shared__ float sc[8];
    float* L0 = ws + OFF_L0; float* U0 = ws + OFF_U0;
    int tid = threadIdx.x;
    if (tid == 0){
        sc[0] = tanhf(Xlb_p[0])*0.5f; sc[1] = tanhf(Xlb_p[1])*0.5f;
        sc[2] = tanhf(Xub_p[0])*0.5f; sc[3] = tanhf(Xub_p[1])*0.5f;
        sc[4] = tanhf(slb_p[0])*0.5f; sc[5] = tanhf(sub_p[0])*0.5f;
        sc[6] = tanhf(tgt_p[0]);
    }
    __syncthreads();
    for (int r = tid; r < 769; r += 256){
        float l = -BIGINF, u = BIGINF;
        if (r < 9){ l = 0.f; u = 0.f; }
        else if (r < R_XUB){ l = -1.f + sc[(r - R_XLB) & 1]; }
        else if (r < R_UBOX){ u = 1.f + sc[2 + ((r - R_XUB) & 1)]; }
        else if (r < R_UEQ){ l = -1.f; u = 1.f; }
        else if (r < R_SLB){ l = 0.f; u = 0.f; }
        else if (r < R_SUB){ l = sc[4]; }
        else if (r < R_TGT){ u = 6.f + sc[5]; }
        else if (r == R_TGT){ l = 1.f + sc[6]; }
        else { l = 0.f; }
        L0[r] = l; U0[r] = u;
    }
}

// 16-lane broadcast of lane J's value within each 16-lane group (BitMode swizzle)
#define SWZB(x, J) __int_as_float(__builtin_amdgcn_ds_swizzle(__float_as_int(x), (((J)<<5)|0x10)))
#define X14(M) M(0) M(1) M(2) M(3) M(4) M(5) M(6) M(7) M(8) M(9) M(10) M(11) M(12) M(13)

// ---------------- K7: persistent fused ADMM, block-tridiag solve in-loop ----------------
// 512 blocks x 256 thr, ROWS=2 batch rows/block (2 blocks/CU -> solve of one block
// overlaps phases A/B of the co-resident block). Solve: 16 lanes/row, c_t in registers,
// ds_swizzle broadcasts, factors (GT fwd / G,Sinv bwd) streamed from L2.
__global__ __launch_bounds__(256, 2) void k_admm(const float* __restrict__ feat,
                                                 const float* __restrict__ XtoZ,
                                                 const float* __restrict__ ws,
                                                 float* __restrict__ out){
    const float* crv = ws + OFF_CSRV; const int* crc = (const int*)(ws + OFF_CSRC);
    const float* ccv = ws + OFF_CSCV; const int* ccr = (const int*)(ws + OFF_CSCR);
    const float* Gp  = ws + OFF_G;
    const float* GT  = ws + OFF_GT;
    const float* SV  = ws + OFF_SINV;
    const float* L0 = ws + OFF_L0; const float* U0 = ws + OFF_U0;

    __shared__ __align__(8) float buf[512][ROWS];   // x / rhs (in-place), [col][row]
    __shared__ __align__(8) float yyT[769][ROWS];
    __shared__ __align__(8) float wwT[769][ROWS];   // w = rho*z - y
    __shared__ float l0s[769], u0s[769];
    __shared__ float zi[ROWS][12];                  // z_init(8) + storage0 at [8]
    __shared__ float pr[ROWS][12];                  // prices9

    int tid = threadIdx.x;
    int b0 = blockIdx.x*ROWS;

    for (int i = tid; i < 769; i += 256){ l0s[i] = L0[i]; u0s[i] = U0[i]; }
    for (int i = tid; i < 512*ROWS; i += 256) (&buf[0][0])[i] = 0.f;
    for (int i = tid; i < 769*ROWS; i += 256){ (&yyT[0][0])[i] = 0.f; (&wwT[0][0])[i] = 0.f; }
    if (tid < 12*ROWS){ int r = tid/12, k = tid%12; pr[r][k] = (k < 9) ? feat[(b0+r)*12 + 3 + k] : 0.f; }
    if (tid < ROWS){
        float s0 = feat[(b0+tid)*12 + 0], s1 = feat[(b0+tid)*12 + 1];
        #pragma unroll
        for (int j = 0; j < 8; ++j) zi[tid][j] = s0*XtoZ[j*2 + 0] + s1*XtoZ[j*2 + 1];
        zi[tid][8] = feat[(b0+tid)*12 + 2];
    }
    __syncthreads();

    const int li = tid & 15;       // component lane (0..13 active)
    const int lr = (tid >> 4) & 1; // row within block (solve uses tid<32)

    for (int it = 0; it < NITERS; ++it){
        // -------- phase A: rhs = sigma*x - q + w@A (CSC gather), in-place over buf --------
        for (int c = tid; c < 502; c += 256){
            float r0, r1;
            r0 = SIGMA*buf[c][0]; r1 = SIGMA*buf[c][1];
            int t14 = c/14, s14 = c - t14*14;
            if (c < 490 && s14 == 9){ int pi = t14 >> 2; r0 -= pr[0][pi]; r1 -= pr[1][pi]; }
            #pragma unroll 4
            for (int s = 0; s < 16; ++s){
                float v = ccv[c*16 + s]; int rr = ccr[c*16 + s];
                r0 += v*wwT[rr][0]; r1 += v*wwT[rr][1];
            }
            buf[c][0] = r0; buf[c][1] = r1;
        }
        __syncthreads();
        // -------- block-tridiagonal solve: x = M^{-1} rhs  (2 rows x 16 lanes) --------
        if (tid < 32){
            float cr[36];
            cr[0] = buf[li][lr];                    // c_0 = b_0
            #pragma unroll
            for (int t = 1; t < 36; ++t){
                const float* gt = GT + t*196 + li;
                float cp = cr[t-1];
                float a0 = buf[14*t + li][lr], a1 = 0.f;
#define FWD1(J) (((J)&1) ? a1 : a0) = fmaf(-gt[(J)*14], SWZB(cp, J), (((J)&1) ? a1 : a0));
                X14(FWD1)
#undef FWD1
                cr[t] = a0 + a1;
            }
            float xp;
            {   // t = 35
                const float* sv = SV + 35*196 + li;
                float ct = cr[35];
                float a0 = 0.f, a1 = 0.f;
#define BW1(J) (((J)&1) ? a1 : a0) = fmaf(sv[(J)*14], SWZB(ct, J), (((J)&1) ? a1 : a0));
                X14(BW1)
#undef BW1
                xp = a0 + a1;
                if (li < 14) buf[490 + li][lr] = xp;
            }
            #pragma unroll
            for (int t = 34; t >= 0; --t){
                const float* sv = SV + t*196 + li;
                const float* gn = Gp + (t+1)*196 + li;
                float ct = cr[t];
                float a0=0.f, a1=0.f, d0=0.f, d1=0.f;
#define BW2(J) (((J)&1) ? a1 : a0) = fmaf(sv[(J)*14], SWZB(ct, J), (((J)&1) ? a1 : a0)); \
               (((J)&1) ? d1 : d0) = fmaf(gn[(J)*14], SWZB(xp, J), (((J)&1) ? d1 : d0));
                X14(BW2)
#undef BW2
                float xn = (a0 + a1) - (d0 + d1);
                if (li < 14) buf[14*t + li][lr] = xn;
                xp = xn;
            }
        }
        __syncthreads();
        // -------- phase B: Ax (CSR), z = clip, y update, w update --------
        for (int rr = tid; rr < 769; rr += 256){
            float rho = rho_of(rr);
            float rinv = 1.f/rho;
            float ax0 = 0.f, ax1 = 0.f;
            #pragma unroll 4
            for (int s = 0; s < 12; ++s){
                float v = crv[rr*12 + s]; int cc = crc[rr*12 + s];
                ax0 += v*buf[cc][0]; ax1 += v*buf[cc][1];
            }
            float lb = 0.f, ub = 0.f;
            if (rr >= 9){ lb = l0s[rr]; ub = u0s[rr]; }
            float yv0 = yyT[rr][0], yv1 = yyT[rr][1];
            float li0, ui0, li1, ui1;
            if (rr < 9){ li0 = ui0 = zi[0][rr]; li1 = ui1 = zi[1][rr]; }
            else { li0 = li1 = lb; ui0 = ui1 = ub; }
            float v0 = ax0 + yv0*rinv;
            float v1 = ax1 + yv1*rinv;
            float z0 = fminf(fmaxf(v0, li0), ui0);
            float z1 = fminf(fmaxf(v1, li1), ui1);
            float yn0 = yv0 + rho*(ax0 - z0);
            float yn1 = yv1 + rho*(ax1 - z1);
            yyT[rr][0] = yn0; yyT[rr][1] = yn1;
            wwT[rr][0] = rho*z0 - yn0; wwT[rr][1] = rho*z1 - yn1;
        }
        __syncthreads();
    }
    // mu = x[:, NUOFF:NUOFF+2] -> permuted cols 8,9
    if (tid < ROWS*2){ int r = tid >> 1, k = tid & 1; out[(b0 + r)*2 + k] = buf[8 + k][r]; }
}

// ---------------- K8: critic MLP ----------------
__global__ __launch_bounds__(64) void k_critic(const float* __restrict__ feat,
    const float* __restrict__ Ws,  const float* __restrict__ bs_,
    const float* __restrict__ Wst, const float* __restrict__ bst,
    const float* __restrict__ Wipr,const float* __restrict__ bipr,
    const float* __restrict__ Wp,  const float* __restrict__ bp,
    const float* __restrict__ Ws1, const float* __restrict__ bs1,
    const float* __restrict__ Wst1,const float* __restrict__ bst1,
    const float* __restrict__ Wipr1,const float* __restrict__ bipr1,
    const float* __restrict__ Wp1, const float* __restrict__ bp1,
    const float* __restrict__ Wf1, const float* __restrict__ bf1,
    const float* __restrict__ Wf2, const float* __restrict__ bf2,
    float* __restrict__ out){
    __shared__ float hL[64][65];
    __shared__ float h2L[64][65];
    int tid = threadIdx.x;
    int b = blockIdx.x*64 + tid;
    const float* f = feat + b*12;
    float st0 = f[0], st1 = f[1], sg = f[2];
    float p[9];
    #pragma unroll
    for (int j = 0; j < 9; ++j) p[j] = f[3 + j];
    float pmx = p[0], pmn = p[0];
    #pragma unroll
    for (int j = 1; j < 9; ++j){ pmx = fmaxf(pmx, p[j]); pmn = fminf(pmn, p[j]); }
    float t1[24], t2[8];
    #pragma unroll
    for (int o = 0; o < 24; ++o) t1[o] = fmaxf(0.f, st0*Ws[o*2] + st1*Ws[o*2 + 1] + bs_[o]);
    #pragma unroll
    for (int o = 0; o < 24; ++o){ float a = bs1[o];
        #pragma unroll
        for (int j = 0; j < 24; ++j) a += t1[j]*Ws1[o*24 + j];
        hL[tid][o] = fmaxf(0.f, a); }
    #pragma unroll
    for (int o = 0; o < 8; ++o) t2[o] = fmaxf(0.f, sg*Wst[o] + bst[o]);
    #pragma unroll
    for (int o = 0; o < 8; ++o){ float a = bst1[o];
        #pragma unroll
        for (int j = 0; j < 8; ++j) a += t2[j]*Wst1[o*8 + j];
        hL[tid][24 + o] = fmaxf(0.f, a); }
    float i1 = pmx - pmn;
    #pragma unroll
    for (int o = 0; o < 8; ++o) t2[o] = fmaxf(0.f, p[0]*Wipr[o*2] + i1*Wipr[o*2 + 1] + bipr[o]);
    #pragma unroll
    for (int o = 0; o < 8; ++o){ float a = bipr1[o];
        #pragma unroll
        for (int j = 0; j < 8; ++j) a += t2[j]*Wipr1[o*8 + j];
        hL[tid][32 + o] = fmaxf(0.f, a); }
    #pragma unroll
    for (int o = 0; o < 24; ++o){ float a = bp[o];
        #pragma unroll
        for (int j = 0; j < 9; ++j) a += p[j]*Wp[o*9 + j];
        t1[o] = fmaxf(0.f, a); }
    #pragma unroll
    for (int o = 0; o < 24; ++o){ float a = bp1[o];
        #pragma unroll
        for (int j = 0; j < 24; ++j) a += t1[j]*Wp1[o*24 + j];
        hL[tid][40 + o] = fmaxf(0.f, a); }
    for (int o = 0; o < 64; ++o){ float a = bf1[o];
        for (int j = 0; j < 64; ++j) a += hL[tid][j]*Wf1[o*64 + j];
        h2L[tid][o] = fmaxf(0.f, a); }
    for (int o = 0; o < 64; ++o){ float a = bf2[o];
        for (int j = 0; j < 64; ++j) a += h2L[tid][j]*Wf2[o*64 + j];
        out[2048 + b*64 + o] = fmaxf(0.f, a); }
}

extern "C" void kernel_launch(void* const* d_in, const int* in_sizes, int n_in,
                              void* d_out, int out_size, void* d_ws, size_t ws_size,
                              hipStream_t stream){
    (void)in_sizes; (void)n_in; (void)out_size; (void)ws_size;
    const float* feat  = (const float*)d_in[0];
    const float* Xlb_p = (const float*)d_in[1];
    const float* Xub_p = (const float*)d_in[2];
    const float* slb_p = (const float*)d_in[3];
    const float* sub_p = (const float*)d_in[4];
    const float* tgt_p = (const float*)d_in[5];
    const float* Az    = (const float*)d_in[6];
    const float* Au    = (const float*)d_in[7];
    const float* ZtoX  = (const float*)d_in[8];
    const float* XtoZ  = (const float*)d_in[9];
    float* ws  = (float*)d_ws;
    float* out = (float*)d_out;

    hipLaunchKernelGGL(k_build_A, dim3(1),    dim3(256), 0, stream, Az, Au, ZtoX, ws);
    hipLaunchKernelGGL(k_sparse,  dim3(5),    dim3(256), 0, stream, ws);
    hipLaunchKernelGGL(k_build_M, dim3(1004), dim3(256), 0, stream, ws);
    hipLaunchKernelGGL(k_factor,  dim3(1),    dim3(256), 0, stream, ws);
    hipLaunchKernelGGL(k_gt,      dim3(28),   dim3(256), 0, stream, ws);
    hipLaunchKernelGGL(k_bounds,  dim3(1),    dim3(256), 0, stream, Xlb_p, Xub_p, slb_p, sub_p, tgt_p, ws);
    hipLaunchKernelGGL(k_admm,    dim3(512),  dim3(256), 0, stream, feat, XtoZ, ws, out);
    hipLaunchKernelGGL(k_critic,  dim3(16),   dim3(64),  0, stream, feat,
        (const float*)d_in[10], (const float*)d_in[11], (const float*)d_in[12], (const float*)d_in[13],
        (const float*)d_in[14], (const float*)d_in[15], (const float*)d_in[16], (const float*)d_in[17],
        (const float*)d_in[18], (const float*)d_in[19], (const float*)d_in[20], (const float*)d_in[21],
        (const float*)d_in[22], (const float*)d_in[23], (const float*)d_in[24], (const float*)d_in[25],
        (const float*)d_in[26], (const float*)d_in[27], (const float*)d_in[28], (const float*)d_in[29],
        out);
}

// Round 6
// 3862.695 us; speedup vs baseline: 16.0610x; 16.0610x over previous
//
#include <hip/hip_runtime.h>
#include <math.h>

// ---------------- problem constants ----------------
#define NZ 8
#define T_H 36
#define NVAR 502        // permuted variable count
#define MCON 769
#define NITERS 150
#define SIGMA 1e-6f
#define BIGINF 1e20f
#define ROWS 2          // batch rows per ADMM block

// constraint row offsets
#define R_XLB 9
#define R_XUB 81
#define R_UBOX 153
#define R_UEQ 223
#define R_DYN 275
#define R_SDYN 555
#define R_SLB 590
#define R_SUB 625
#define R_TGT 660
#define R_XSNN 661
#define R_SSNN 733

// global-var offsets (original ordering)
#define NUOFF 288
#define NSOFF 358
#define NXSOFF 394
#define NSSOFF 466

// ws layout (float offsets)
#define OFF_A      0          // A[769][512] permuted cols
#define OFF_CSRV   393728     // [769][12]
#define OFF_CSRC   402956     // [769][12] ints
#define OFF_CSCV   412184     // [502][16]
#define OFF_CSCR   420216     // [502][16] ints
#define OFF_M      428248     // M[502][512]
#define OFF_SINV   685272     // 36 * 196   Sinv_t (symmetric, zero-padded)
#define OFF_G      692328     // 36 * 196   G_t[i][j] (t>=1 used)
#define OFF_GP     699384     // 36*16*16   G rows padded  (fwd:  row li = G[li][j])
#define OFF_GTP    708600     // 36*16*16   G^T rows padded (bwd: row li = G[j][li])
#define OFF_SVP    717816     // 36*16*16   Sinv rows padded
#define OFF_L0     956408     // [769]
#define OFF_U0     957177     // [769]

// permuted column: per-timestep blocks [z(8), u(2), s(1), xs(2), ss(1)], t=35 has no u
__device__ __forceinline__ int pcol(int v){
    if (v < 288){ int t = v >> 3, j = v & 7; return 14*t + j; }
    if (v < 358){ int q = v - 288; int t = q >> 1, k = q & 1; return 14*t + 8 + k; }
    if (v < 394){ int t = v - 358; return (t < 35) ? (14*t + 10) : 498; }
    if (v < 466){ int q = v - 394; int t = q >> 1, k = q & 1; return (t < 35) ? (14*t + 11 + k) : (499 + k); }
    int t = v - 466; return (t < 35) ? (14*t + 13) : 501;
}

__device__ __forceinline__ float rho_of(int r){
    if (r <= 8) return 1000.f;
    if (r >= R_UEQ && r < R_SLB) return 1000.f;   // ueq, dyn, sdyn
    return 1.f;
}

__device__ __forceinline__ float pdiag_p(int p){
    if (p < 490){ int s = p % 14; return (s >= 11) ? 20000.f : 0.f; }
    int s = p - 490; return (s >= 9) ? 20000.f : 0.f;
}

// ---------------- K1: build permuted dense A ----------------
__global__ __launch_bounds__(256) void k_build_A(const float* __restrict__ Az,
                                                 const float* __restrict__ Au,
                                                 const float* __restrict__ ZtoX,
                                                 float* __restrict__ ws){
    float* A = ws + OFF_A;
    int tid = threadIdx.x;
    for (int i = tid; i < 769*512; i += 256) A[i] = 0.f;
    __syncthreads();
    for (int i = tid; i < 8; i += 256) A[i*512 + pcol(i)] += 1.f;
    if (tid == 0) A[8*512 + pcol(NSOFF)] += 1.f;
    for (int idx = tid; idx < 576; idx += 256){
        int t = idx >> 4, k = (idx >> 3) & 1, j = idx & 7;
        float v = ZtoX[k*8 + j];
        int c = pcol(8*t + j);
        A[(R_XLB + 2*t + k)*512 + c] += v;
        A[(R_XUB + 2*t + k)*512 + c] += v;
    }
    for (int idx = tid; idx < 72; idx += 256){
        int c = pcol(NXSOFF + idx);
        A[(R_XLB + idx)*512 + c] += 1.f;
        A[(R_XUB + idx)*512 + c] -= 1.f;
    }
    for (int idx = tid; idx < 70; idx += 256) A[(R_UBOX + idx)*512 + pcol(NUOFF + idx)] += 1.f;
    for (int idx = tid; idx < 52; idx += 256){
        int i = idx >> 1, kk = idx & 1;
        int t = (i/3)*4 + (i%3) + 1;
        A[(R_UEQ + idx)*512 + pcol(NUOFF + 2*t + kk)]       += 1.f;
        A[(R_UEQ + idx)*512 + pcol(NUOFF + 2*(t-1) + kk)]   -= 1.f;
    }
    for (int idx = tid; idx < 2240; idx += 256){
        int t = idx/64 + 1, rem = idx % 64, j = rem >> 3, k = rem & 7;
        A[(R_DYN + 8*(t-1) + j)*512 + pcol(8*(t-1) + k)] += Az[j*8 + k];
    }
    for (int idx = tid; idx < 560; idx += 256){
        int t = idx/16 + 1, rem = idx % 16, j = rem >> 1, ju = rem & 1;
        A[(R_DYN + 8*(t-1) + j)*512 + pcol(NUOFF + 2*(t-1) + ju)] += Au[j*2 + ju];
    }
    for (int idx = tid; idx < 280; idx += 256){
        int t = (idx >> 3) + 1, j = idx & 7;
        A[(R_DYN + 8*(t-1) + j)*512 + pcol(8*t + j)] -= 1.f;
    }
    for (int idx = tid; idx < 35; idx += 256){
        int t = idx + 1; int rb = (R_SDYN + idx)*512;
        A[rb + pcol(NSOFF + t)]     += 1.f;
        A[rb + pcol(NSOFF + t - 1)] -= 1.f;
        A[rb + pcol(NUOFF + 2*(t-1))] += -0.05f;   // -0.2/NCC
    }
    for (int idx = tid; idx < 35; idx += 256){
        int t = idx + 1;
        A[(R_SLB + idx)*512 + pcol(NSOFF + t)]  += 1.f;
        A[(R_SLB + idx)*512 + pcol(NSSOFF + t)] += 1.f;
        A[(R_SUB + idx)*512 + pcol(NSOFF + t)]  += 1.f;
        A[(R_SUB + idx)*512 + pcol(NSSOFF + t)] -= 1.f;
    }
    if (tid == 0){
        A[R_TGT*512 + pcol(NSOFF + 35)]  += 1.f;
        A[R_TGT*512 + pcol(NSSOFF + 35)] += 1.f;
    }
    for (int idx = tid; idx < 72; idx += 256) A[(R_XSNN + idx)*512 + pcol(NXSOFF + idx)] += 1.f;
    for (int idx = tid; idx < 36; idx += 256) A[(R_SSNN + idx)*512 + pcol(NSSOFF + idx)] += 1.f;
}

// ---------------- K2: CSR(12) / CSC(16) from dense A ----------------
__global__ __launch_bounds__(256) void k_sparse(float* __restrict__ ws){
    const float* A = ws + OFF_A;
    float* crv = ws + OFF_CSRV; int* crc = (int*)(ws + OFF_CSRC);
    float* ccv = ws + OFF_CSCV; int* ccr = (int*)(ws + OFF_CSCR);
    int job = blockIdx.x*256 + threadIdx.x;
    if (job < 769){
        int r = job, n = 0;
        for (int c = 0; c < 502; ++c){
            float v = A[r*512 + c];
            if (v != 0.f && n < 12){ crv[r*12 + n] = v; crc[r*12 + n] = c; ++n; }
        }
        for (; n < 12; ++n){ crv[r*12 + n] = 0.f; crc[r*12 + n] = 0; }
    } else if (job < 1271){
        int c = job - 769, n = 0;
        for (int r = 0; r < 769; ++r){
            float v = A[r*512 + c];
            if (v != 0.f && n < 16){ ccv[c*16 + n] = v; ccr[c*16 + n] = r; ++n; }
        }
        for (; n < 16; ++n){ ccv[c*16 + n] = 0.f; ccr[c*16 + n] = 0; }
    }
}

// ---------------- K3: M = diag(P+sigma) + A^T rho A (permuted) ----------------
__global__ __launch_bounds__(256) void k_build_M(float* __restrict__ ws){
    const float* A = ws + OFF_A;
    const float* ccv = ws + OFF_CSCV; const int* ccr = (const int*)(ws + OFF_CSCR);
    float* M = ws + OFF_M;
    int gid = blockIdx.x*256 + threadIdx.x;
    int i = gid >> 9, j = gid & 511;
    if (j >= 502) return;
    float acc = 0.f;
    #pragma unroll
    for (int s = 0; s < 16; ++s){
        float v = ccv[i*16 + s]; int r = ccr[i*16 + s];
        acc += v * rho_of(r) * A[r*512 + j];
    }
    if (i == j) acc += pdiag_p(i) + SIGMA;
    M[i*512 + j] = acc;
}

// ---------------- K4: block-tridiagonal LDL factor (sequential over t) ----------------
__global__ __launch_bounds__(256) void k_factor(float* __restrict__ ws){
    const float* M = ws + OFF_M;
    float* Gout = ws + OFF_G;
    float* Sout = ws + OFF_SINV;
    __shared__ float Sp[196], Dl[196], Gl[196], fcol[14];
    __shared__ float aug[14*28];
    __shared__ float piv;
    int tid = threadIdx.x;
    for (int t = 0; t < 36; ++t){
        int bs = (t < 35) ? 14 : 12;
        int bo = 14*t;
        for (int idx = tid; idx < bs*bs; idx += 256){ int i = idx/bs, j = idx%bs; aug[i*28 + j] = M[(bo+i)*512 + bo + j]; }
        for (int idx = tid; idx < bs*bs; idx += 256){ int i = idx/bs, j = idx%bs; aug[i*28 + 14 + j] = (i==j) ? 1.f : 0.f; }
        if (t > 0){
            for (int idx = tid; idx < 196; idx += 256){ int i = idx/14, j = idx%14; Dl[idx] = (i < bs) ? M[(bo+i)*512 + (bo-14) + j] : 0.f; }
            __syncthreads();
            for (int idx = tid; idx < 196; idx += 256){
                int i = idx/14, j = idx%14; float a = 0.f;
                #pragma unroll
                for (int k = 0; k < 14; ++k) a += Dl[i*14 + k]*Sp[k*14 + j];
                Gl[idx] = a; Gout[t*196 + idx] = a;
            }
            __syncthreads();
            for (int idx = tid; idx < bs*bs; idx += 256){
                int i = idx/bs, j = idx%bs; float a = 0.f;
                #pragma unroll
                for (int k = 0; k < 14; ++k) a += Gl[i*14 + k]*Dl[j*14 + k];
                aug[i*28 + j] -= a;
            }
        }
        __syncthreads();
        for (int k = 0; k < bs; ++k){
            if (tid == 0) piv = 1.f/aug[k*28 + k];
            if (tid < bs) fcol[tid] = aug[tid*28 + k];
            __syncthreads();
            for (int j = tid; j < 2*bs; j += 256){ int col = (j < bs) ? j : (14 + j - bs); aug[k*28 + col] *= piv; }
            __syncthreads();
            for (int idx = tid; idx < bs*2*bs; idx += 256){
                int i = idx/(2*bs), jj = idx%(2*bs);
                int col = (jj < bs) ? jj : (14 + jj - bs);
                if (i != k) aug[i*28 + col] -= fcol[i]*aug[k*28 + col];
            }
            __syncthreads();
        }
        for (int idx = tid; idx < 196; idx += 256){
            int i = idx/14, j = idx%14;
            float v = (i < bs && j < bs) ? aug[i*28 + 14 + j] : 0.f;
            Sout[t*196 + idx] = v; Sp[idx] = v;
        }
        __syncthreads();
    }
}

// ---------------- K5: pack factors into padded [36][16][16] float4-friendly rows ----------------
__global__ __launch_bounds__(256) void k_pack(float* __restrict__ ws){
    int t = blockIdx.x;          // 36 blocks
    int e = threadIdx.x;         // 16*16
    int i = e >> 4, j = e & 15;
    bool in = (i < 14) && (j < 14);
    float g  = in ? ws[OFF_G    + t*196 + i*14 + j] : 0.f;
    float gt = in ? ws[OFF_G    + t*196 + j*14 + i] : 0.f;
    float sv = in ? ws[OFF_SINV + t*196 + i*14 + j] : 0.f;
    ws[OFF_GP  + (t*16 + i)*16 + j] = g;
    ws[OFF_GTP + (t*16 + i)*16 + j] = gt;
    ws[OFF_SVP + (t*16 + i)*16 + j] = sv;
}

// ---------------- K6: batch-uniform bounds ----------------
__global__ __launch_bounds__(256) void k_bounds(const float* __restrict__ Xlb_p, const float* __restrict__ Xub_p,
                                                const float* __restrict__ slb_p, const float* __restrict__ sub_p,
                                                const float* __restrict__ tgt_p, float* __restrict__ ws){
    __shared__ float sc[8];
    float* L0 = ws + OFF_L0; float* U0 = ws + OFF_U0;
    int tid = threadIdx.x;
    if (tid == 0){
        sc[0] = tanhf(Xlb_p[0])*0.5f; sc[1] = tanhf(Xlb_p[1])*0.5f;
        sc[2] = tanhf(Xub_p[0])*0.5f; sc[3] = tanhf(Xub_p[1])*0.5f;
        sc[4] = tanhf(slb_p[0])*0.5f; sc[5] = tanhf(sub_p[0])*0.5f;
        sc[6] = tanhf(tgt_p[0]);
    }
    __syncthreads();
    for (int r = tid; r < 769; r += 256){
        float l = -BIGINF, u = BIGINF;
        if (r < 9){ l = 0.f; u = 0.f; }
        else if (r < R_XUB){ l = -1.f + sc[(r - R_XLB) & 1]; }
        else if (r < R_UBOX){ u = 1.f + sc[2 + ((r - R_XUB) & 1)]; }
        else if (r < R_UEQ){ l = -1.f; u = 1.f; }
        else if (r < R_SLB){ l = 0.f; u = 0.f; }
        else if (r < R_SUB){ l = sc[4]; }
        else if (r < R_TGT){ u = 6.f + sc[5]; }
        else if (r == R_TGT){ l = 1.f + sc[6]; }
        else { l = 0.f; }
        L0[r] = l; U0[r] = u;
    }
}

// ---------------- K7: persistent fused ADMM, block-tridiag solve in-loop ----------------
// 512 blocks x 256 thr, ROWS=2. Solve: single wave (tid<32), 16 lanes/row; carry
// vectors in small LDS buffers (crb/xb) -> no register arrays, no spills; factors
// read as float4 rows of padded [36][16][16] global arrays (L2-resident, rolled loops).
__global__ __launch_bounds__(256) void k_admm(const float* __restrict__ feat,
                                              const float* __restrict__ XtoZ,
                                              const float* __restrict__ ws,
                                              float* __restrict__ out){
    const float* crv = ws + OFF_CSRV; const int* crc = (const int*)(ws + OFF_CSRC);
    const float* ccv = ws + OFF_CSCV; const int* ccr = (const int*)(ws + OFF_CSCR);
    const float* GP  = ws + OFF_GP;
    const float* GTP = ws + OFF_GTP;
    const float* SVP = ws + OFF_SVP;
    const float* L0 = ws + OFF_L0; const float* U0 = ws + OFF_U0;

    __shared__ __align__(16) float buf[512][ROWS];     // x / rhs (in-place), [col][row]
    __shared__ __align__(16) float yyT[769][ROWS];
    __shared__ __align__(16) float wwT[769][ROWS];     // w = rho*z - y
    __shared__ __align__(16) float crb[36][ROWS][20];  // forward carry c_t (padded rows)
    __shared__ __align__(16) float xb[ROWS][20];       // backward carry x_{t+1}
    __shared__ float l0s[769], u0s[769];
    __shared__ float zi[ROWS][12];                     // z_init(8) + storage0 at [8]
    __shared__ float pr[ROWS][12];                     // prices9

    int tid = threadIdx.x;
    int b0 = blockIdx.x*ROWS;

    for (int i = tid; i < 769; i += 256){ l0s[i] = L0[i]; u0s[i] = U0[i]; }
    for (int i = tid; i < 512*ROWS; i += 256) (&buf[0][0])[i] = 0.f;
    for (int i = tid; i < 769*ROWS; i += 256){ (&yyT[0][0])[i] = 0.f; (&wwT[0][0])[i] = 0.f; }
    for (int i = tid; i < 36*ROWS*20; i += 256) (&crb[0][0][0])[i] = 0.f;
    if (tid < ROWS*20) (&xb[0][0])[tid] = 0.f;
    if (tid < 12*ROWS){ int r = tid/12, k = tid%12; pr[r][k] = (k < 9) ? feat[(b0+r)*12 + 3 + k] : 0.f; }
    if (tid < ROWS){
        float s0 = feat[(b0+tid)*12 + 0], s1 = feat[(b0+tid)*12 + 1];
        #pragma unroll
        for (int j = 0; j < 8; ++j) zi[tid][j] = s0*XtoZ[j*2 + 0] + s1*XtoZ[j*2 + 1];
        zi[tid][8] = feat[(b0+tid)*12 + 2];
    }
    __syncthreads();

    for (int it = 0; it < NITERS; ++it){
        // -------- phase A: rhs = sigma*x - q + w@A (CSC gather), in-place over buf --------
        for (int c = tid; c < 502; c += 256){
            float r0, r1;
            r0 = SIGMA*buf[c][0]; r1 = SIGMA*buf[c][1];
            int t14 = c/14, s14 = c - t14*14;
            if (c < 490 && s14 == 9){ int pi = t14 >> 2; r0 -= pr[0][pi]; r1 -= pr[1][pi]; }
            #pragma unroll 4
            for (int s = 0; s < 16; ++s){
                float v = ccv[c*16 + s]; int rr = ccr[c*16 + s];
                r0 += v*wwT[rr][0]; r1 += v*wwT[rr][1];
            }
            buf[c][0] = r0; buf[c][1] = r1;
        }
        __syncthreads();
        // -------- block-tridiagonal solve: x = M^{-1} rhs (single wave, 2 rows x 16 lanes) --------
        if (tid < 32){
            const int li = tid & 15;
            const int lr = tid >> 4;
            // t = 0
            crb[0][lr][li] = (li < 14) ? buf[li][lr] : 0.f;
            // forward: c_t = b_t - G_t c_{t-1}
            for (int t = 1; t < 36; ++t){
                const float* gr = GP + (t*16 + li)*16;
                float4 g0 = *(const float4*)(gr + 0);
                float4 g1 = *(const float4*)(gr + 4);
                float4 g2 = *(const float4*)(gr + 8);
                float4 g3 = *(const float4*)(gr + 12);
                float4 c0 = *(const float4*)&crb[t-1][lr][0];
                float4 c1 = *(const float4*)&crb[t-1][lr][4];
                float4 c2 = *(const float4*)&crb[t-1][lr][8];
                float4 c3 = *(const float4*)&crb[t-1][lr][12];
                float a0 = (li < 14) ? buf[14*t + li][lr] : 0.f;
                float a1 = 0.f;
                a0 = fmaf(-g0.x, c0.x, a0); a1 = fmaf(-g0.y, c0.y, a1);
                a0 = fmaf(-g0.z, c0.z, a0); a1 = fmaf(-g0.w, c0.w, a1);
                a0 = fmaf(-g1.x, c1.x, a0); a1 = fmaf(-g1.y, c1.y, a1);
                a0 = fmaf(-g1.z, c1.z, a0); a1 = fmaf(-g1.w, c1.w, a1);
                a0 = fmaf(-g2.x, c2.x, a0); a1 = fmaf(-g2.y, c2.y, a1);
                a0 = fmaf(-g2.z, c2.z, a0); a1 = fmaf(-g2.w, c2.w, a1);
                a0 = fmaf(-g3.x, c3.x, a0); a1 = fmaf(-g3.y, c3.y, a1);
                a0 = fmaf(-g3.z, c3.z, a0); a1 = fmaf(-g3.w, c3.w, a1);
                crb[t][lr][li] = a0 + a1;
            }
            // backward t = 35: x = Sinv_35 c_35
            {
                const float* sr = SVP + (35*16 + li)*16;
                float4 s0 = *(const float4*)(sr + 0);
                float4 s1 = *(const float4*)(sr + 4);
                float4 s2 = *(const float4*)(sr + 8);
                float4 s3 = *(const float4*)(sr + 12);
                float4 c0 = *(const float4*)&crb[35][lr][0];
                float4 c1 = *(const float4*)&crb[35][lr][4];
                float4 c2 = *(const float4*)&crb[35][lr][8];
                float4 c3 = *(const float4*)&crb[35][lr][12];
                float a0 = 0.f, a1 = 0.f;
                a0 = fmaf(s0.x, c0.x, a0); a1 = fmaf(s0.y, c0.y, a1);
                a0 = fmaf(s0.z, c0.z, a0); a1 = fmaf(s0.w, c0.w, a1);
                a0 = fmaf(s1.x, c1.x, a0); a1 = fmaf(s1.y, c1.y, a1);
                a0 = fmaf(s1.z, c1.z, a0); a1 = fmaf(s1.w, c1.w, a1);
                a0 = fmaf(s2.x, c2.x, a0); a1 = fmaf(s2.y, c2.y, a1);
                a0 = fmaf(s2.z, c2.z, a0); a1 = fmaf(s2.w, c2.w, a1);
                a0 = fmaf(s3.x, c3.x, a0); a1 = fmaf(s3.y, c3.y, a1);
                a0 = fmaf(s3.z, c3.z, a0); a1 = fmaf(s3.w, c3.w, a1);
                float x = a0 + a1;
                xb[lr][li] = x;
                if (li < 14) buf[490 + li][lr] = x;
            }
            // backward t = 34..0: x_t = Sinv_t c_t - G_{t+1}^T x_{t+1}
            for (int t = 34; t >= 0; --t){
                const float* sr = SVP + (t*16 + li)*16;
                const float* tr = GTP + ((t+1)*16 + li)*16;
                float4 s0 = *(const float4*)(sr + 0);
                float4 s1 = *(const float4*)(sr + 4);
                float4 s2 = *(const float4*)(sr + 8);
                float4 s3 = *(const float4*)(sr + 12);
                float4 t0 = *(const float4*)(tr + 0);
                float4 t1 = *(const float4*)(tr + 4);
                float4 t2 = *(const float4*)(tr + 8);
                float4 t3 = *(const float4*)(tr + 12);
                float4 c0 = *(const float4*)&crb[t][lr][0];
                float4 c1 = *(const float4*)&crb[t][lr][4];
                float4 c2 = *(const float4*)&crb[t][lr][8];
                float4 c3 = *(const float4*)&crb[t][lr][12];
                float4 x0 = *(const float4*)&xb[lr][0];
                float4 x1 = *(const float4*)&xb[lr][4];
                float4 x2 = *(const float4*)&xb[lr][8];
                float4 x3 = *(const float4*)&xb[lr][12];
                float a0 = 0.f, a1 = 0.f, d0 = 0.f, d1 = 0.f;
                a0 = fmaf(s0.x, c0.x, a0); a1 = fmaf(s0.y, c0.y, a1);
                a0 = fmaf(s0.z, c0.z, a0); a1 = fmaf(s0.w, c0.w, a1);
                a0 = fmaf(s1.x, c1.x, a0); a1 = fmaf(s1.y, c1.y, a1);
                a0 = fmaf(s1.z, c1.z, a0); a1 = fmaf(s1.w, c1.w, a1);
                a0 = fmaf(s2.x, c2.x, a0); a1 = fmaf(s2.y, c2.y, a1);
                a0 = fmaf(s2.z, c2.z, a0); a1 = fmaf(s2.w, c2.w, a1);
                a0 = fmaf(s3.x, c3.x, a0); a1 = fmaf(s3.y, c3.y, a1);
                a0 = fmaf(s3.z, c3.z, a0); a1 = fmaf(s3.w, c3.w, a1);
                d0 = fmaf(t0.x, x0.x, d0); d1 = fmaf(t0.y, x0.y, d1);
                d0 = fmaf(t0.z, x0.z, d0); d1 = fmaf(t0.w, x0.w, d1);
                d0 = fmaf(t1.x, x1.x, d0); d1 = fmaf(t1.y, x1.y, d1);
                d0 = fmaf(t1.z, x1.z, d0); d1 = fmaf(t1.w, x1.w, d1);
                d0 = fmaf(t2.x, x2.x, d0); d1 = fmaf(t2.y, x2.y, d1);
                d0 = fmaf(t2.z, x2.z, d0); d1 = fmaf(t2.w, x2.w, d1);
                d0 = fmaf(t3.x, x3.x, d0); d1 = fmaf(t3.y, x3.y, d1);
                d0 = fmaf(t3.z, x3.z, d0); d1 = fmaf(t3.w, x3.w, d1);
                float x = (a0 + a1) - (d0 + d1);
                xb[lr][li] = x;
                if (li < 14) buf[14*t + li][lr] = x;
            }
        }
        __syncthreads();
        // -------- phase B: Ax (CSR), z = clip, y update, w update --------
        for (int rr = tid; rr < 769; rr += 256){
            float rho = rho_of(rr);
            float rinv = 1.f/rho;
            float ax0 = 0.f, ax1 = 0.f;
            #pragma unroll 4
            for (int s = 0; s < 12; ++s){
                float v = crv[rr*12 + s]; int cc = crc[rr*12 + s];
                ax0 += v*buf[cc][0]; ax1 += v*buf[cc][1];
            }
            float lb = 0.f, ub = 0.f;
            if (rr >= 9){ lb = l0s[rr]; ub = u0s[rr]; }
            float yv0 = yyT[rr][0], yv1 = yyT[rr][1];
            float li0, ui0, li1, ui1;
            if (rr < 9){ li0 = ui0 = zi[0][rr]; li1 = ui1 = zi[1][rr]; }
            else { li0 = li1 = lb; ui0 = ui1 = ub; }
            float v0 = ax0 + yv0*rinv;
            float v1 = ax1 + yv1*rinv;
            float z0 = fminf(fmaxf(v0, li0), ui0);
            float z1 = fminf(fmaxf(v1, li1), ui1);
            float yn0 = yv0 + rho*(ax0 - z0);
            float yn1 = yv1 + rho*(ax1 - z1);
            yyT[rr][0] = yn0; yyT[rr][1] = yn1;
            wwT[rr][0] = rho*z0 - yn0; wwT[rr][1] = rho*z1 - yn1;
        }
        __syncthreads();
    }
    // mu = x[:, NUOFF:NUOFF+2] -> permuted cols 8,9
    if (tid < ROWS*2){ int r = tid >> 1, k = tid & 1; out[(b0 + r)*2 + k] = buf[8 + k][r]; }
}

// ---------------- K8: critic MLP ----------------
__global__ __launch_bounds__(64) void k_critic(const float* __restrict__ feat,
    const float* __restrict__ Ws,  const float* __restrict__ bs_,
    const float* __restrict__ Wst, const float* __restrict__ bst,
    const float* __restrict__ Wipr,const float* __restrict__ bipr,
    const float* __restrict__ Wp,  const float* __restrict__ bp,
    const float* __restrict__ Ws1, const float* __restrict__ bs1,
    const float* __restrict__ Wst1,const float* __restrict__ bst1,
    const float* __restrict__ Wipr1,const float* __restrict__ bipr1,
    const float* __restrict__ Wp1, const float* __restrict__ bp1,
    const float* __restrict__ Wf1, const float* __restrict__ bf1,
    const float* __restrict__ Wf2, const float* __restrict__ bf2,
    float* __restrict__ out){
    __shared__ float hL[64][65];
    __shared__ float h2L[64][65];
    int tid = threadIdx.x;
    int b = blockIdx.x*64 + tid;
    const float* f = feat + b*12;
    float st0 = f[0], st1 = f[1], sg = f[2];
    float p[9];
    #pragma unroll
    for (int j = 0; j < 9; ++j) p[j] = f[3 + j];
    float pmx = p[0], pmn = p[0];
    #pragma unroll
    for (int j = 1; j < 9; ++j){ pmx = fmaxf(pmx, p[j]); pmn = fminf(pmn, p[j]); }
    float t1[24], t2[8];
    #pragma unroll
    for (int o = 0; o < 24; ++o) t1[o] = fmaxf(0.f, st0*Ws[o*2] + st1*Ws[o*2 + 1] + bs_[o]);
    #pragma unroll
    for (int o = 0; o < 24; ++o){ float a = bs1[o];
        #pragma unroll
        for (int j = 0; j < 24; ++j) a += t1[j]*Ws1[o*24 + j];
        hL[tid][o] = fmaxf(0.f, a); }
    #pragma unroll
    for (int o = 0; o < 8; ++o) t2[o] = fmaxf(0.f, sg*Wst[o] + bst[o]);
    #pragma unroll
    for (int o = 0; o < 8; ++o){ float a = bst1[o];
        #pragma unroll
        for (int j = 0; j < 8; ++j) a += t2[j]*Wst1[o*8 + j];
        hL[tid][24 + o] = fmaxf(0.f, a); }
    float i1 = pmx - pmn;
    #pragma unroll
    for (int o = 0; o < 8; ++o) t2[o] = fmaxf(0.f, p[0]*Wipr[o*2] + i1*Wipr[o*2 + 1] + bipr[o]);
    #pragma unroll
    for (int o = 0; o < 8; ++o){ float a = bipr1[o];
        #pragma unroll
        for (int j = 0; j < 8; ++j) a += t2[j]*Wipr1[o*8 + j];
        hL[tid][32 + o] = fmaxf(0.f, a); }
    #pragma unroll
    for (int o = 0; o < 24; ++o){ float a = bp[o];
        #pragma unroll
        for (int j = 0; j < 9; ++j) a += p[j]*Wp[o*9 + j];
        t1[o] = fmaxf(0.f, a); }
    #pragma unroll
    for (int o = 0; o < 24; ++o){ float a = bp1[o];
        #pragma unroll
        for (int j = 0; j < 24; ++j) a += t1[j]*Wp1[o*24 + j];
        hL[tid][40 + o] = fmaxf(0.f, a); }
    for (int o = 0; o < 64; ++o){ float a = bf1[o];
        for (int j = 0; j < 64; ++j) a += hL[tid][j]*Wf1[o*64 + j];
        h2L[tid][o] = fmaxf(0.f, a); }
    for (int o = 0; o < 64; ++o){ float a = bf2[o];
        for (int j = 0; j < 64; ++j) a += h2L[tid][j]*Wf2[o*64 + j];
        out[2048 + b*64 + o] = fmaxf(0.f, a); }
}

extern "C" void kernel_launch(void* const* d_in, const int* in_sizes, int n_in,
                              void* d_out, int out_size, void* d_ws, size_t ws_size,
                              hipStream_t stream){
    (void)in_sizes; (void)n_in; (void)out_size; (void)ws_size;
    const float* feat  = (const float*)d_in[0];
    const float* Xlb_p = (const float*)d_in[1];
    const float* Xub_p = (const float*)d_in[2];
    const float* slb_p = (const float*)d_in[3];
    const float* sub_p = (const float*)d_in[4];
    const float* tgt_p = (const float*)d_in[5];
    const float* Az    = (const float*)d_in[6];
    const float* Au    = (const float*)d_in[7];
    const float* ZtoX  = (const float*)d_in[8];
    const float* XtoZ  = (const float*)d_in[9];
    float* ws  = (float*)d_ws;
    float* out = (float*)d_out;

    hipLaunchKernelGGL(k_build_A, dim3(1),    dim3(256), 0, stream, Az, Au, ZtoX, ws);
    hipLaunchKernelGGL(k_sparse,  dim3(5),    dim3(256), 0, stream, ws);
    hipLaunchKernelGGL(k_build_M, dim3(1004), dim3(256), 0, stream, ws);
    hipLaunchKernelGGL(k_factor,  dim3(1),    dim3(256), 0, stream, ws);
    hipLaunchKernelGGL(k_pack,    dim3(36),   dim3(256), 0, stream, ws);
    hipLaunchKernelGGL(k_bounds,  dim3(1),    dim3(256), 0, stream, Xlb_p, Xub_p, slb_p, sub_p, tgt_p, ws);
    hipLaunchKernelGGL(k_admm,    dim3(512),  dim3(256), 0, stream, feat, XtoZ, ws, out);
    hipLaunchKernelGGL(k_critic,  dim3(16),   dim3(64),  0, stream, feat,
        (const float*)d_in[10], (const float*)d_in[11], (const float*)d_in[12], (const float*)d_in[13],
        (const float*)d_in[14], (const float*)d_in[15], (const float*)d_in[16], (const float*)d_in[17],
        (const float*)d_in[18], (const float*)d_in[19], (const float*)d_in[20], (const float*)d_in[21],
        (const float*)d_in[22], (const float*)d_in[23], (const float*)d_in[24], (const float*)d_in[25],
        (const float*)d_in[26], (const float*)d_in[27], (const float*)d_in[28], (const float*)d_in[29],
        out);
}